// Round 5
// baseline (1243.845 us; speedup 1.0000x reference)
//
#include <hip/hip_runtime.h>
#include <math.h>

namespace {
constexpr int kB = 2;
constexpr int kM = 512;
constexpr int kN = 2048;
constexpr int kHID = 256;
constexpr int kDH = 32;
constexpr int kL = 4;
constexpr float kEPS = 1e-5f;
constexpr int kKV = 2560; // Kbig rows / Vt_big cols per batch (2048 ks + 512 qs)
constexpr int kNS = 4;    // attention key splits
}

typedef __attribute__((ext_vector_type(8))) short short8;
typedef __attribute__((ext_vector_type(4))) float f32x4;

__device__ inline ushort f2b(float f) {
  unsigned u = __builtin_bit_cast(unsigned, f);
  unsigned r = (u + 0x7fffu + ((u >> 16) & 1u)) >> 16;
  return (ushort)r;
}
__device__ inline float b2f(ushort u) {
  return __builtin_bit_cast(float, (unsigned)u << 16);
}
__device__ inline unsigned cvtpk(float lo, float hi) {
  unsigned r;
  asm("v_cvt_pk_bf16_f32 %0, %1, %2" : "=v"(r) : "v"(lo), "v"(hi));
  return r;
}
__device__ inline void gld16(ushort* lds, const ushort* g) {
  __builtin_amdgcn_global_load_lds(
      (const __attribute__((address_space(1))) void*)g,
      (__attribute__((address_space(3))) void*)lds, 16, 0, 0);
}

// ---------------- mask normalization (dtype sniffing) ----------------
__global__ __launch_bounds__(256) void mask_norm_kernel(
    const unsigned char* __restrict__ mraw, float* __restrict__ mf)
{
  int tid = threadIdx.x;
  __shared__ unsigned sh[4];
  if (tid < 4) sh[tid] = 0;
  __syncthreads();
  unsigned l1 = 0, l2 = 0, l3 = 0, l4 = 0;
  for (int j = 0; j < 16; ++j) {
    int p = tid * 16 + j;
    unsigned v = mraw[p];
    int r = p & 3;
    if (r == 1) l1 |= v;
    else if (r == 2) l2 |= v;
    else if (r == 3) l3 |= v;
    else if ((p & 7) == 4) l4 |= v;
  }
  if (l1) atomicOr(&sh[0], l1);
  if (l2) atomicOr(&sh[1], l2);
  if (l3) atomicOr(&sh[2], l3);
  if (l4) atomicOr(&sh[3], l4);
  __syncthreads();
  unsigned a1 = sh[0], a2 = sh[1], a3 = sh[2], a4 = sh[3];
  int mode; // 0=u8, 1=i32, 2=i64, 3=f32
  if ((a1 | a2 | a3) == 0) mode = a4 ? 1 : 2;
  else if (a1 == 0 && (a2 & ~0x80u) == 0 && (a3 & ~0x3Fu) == 0 && ((a2 | a3) != 0))
    mode = 3;
  else mode = 0;

  int i = blockIdx.x * 256 + tid;
  unsigned char v;
  if (mode == 0) v = mraw[i];
  else if (mode == 1) v = mraw[i * 4];
  else if (mode == 2) v = mraw[i * 8];
  else v = mraw[i * 4 + 3];
  mf[i] = v ? 1.f : 0.f;
}

// ---------------- encoder: sinenc + add + LN1 -> bf16 ----------------
__global__ __launch_bounds__(256) void encode_kernel(
    const float* __restrict__ c2d, const float* __restrict__ f2,
    const float* __restrict__ f3, const float* __restrict__ g,
    const float* __restrict__ bb, ushort* __restrict__ out)
{
  int row = blockIdx.x;
  int c = threadIdx.x;
  float coord = c2d[(size_t)row * 2 + (c >> 7)];
  int h = c & 127;
  float ex = (float)(h & ~1) * (1.0f / 128.0f);
  float inv = expf(ex * 9.210340371976184f); // 10000^ex
  float val = coord / inv;
  float e = (h & 1) ? cosf(val) : sinf(val);
  float x = f2[(size_t)row * 256 + c] + f3[(size_t)row * 256 + c] + e;
  __shared__ float red[256];
  red[c] = x; __syncthreads();
  for (int s = 128; s > 0; s >>= 1) { if (c < s) red[c] += red[c + s]; __syncthreads(); }
  float mean = red[0] * (1.0f / 256.0f);
  __syncthreads();
  float d = x - mean;
  red[c] = d * d; __syncthreads();
  for (int s = 128; s > 0; s >>= 1) { if (c < s) red[c] += red[c + s]; __syncthreads(); }
  float var = red[0] * (1.0f / 256.0f);
  out[(size_t)row * 256 + c] = f2b(d * rsqrtf(var + kEPS) * g[c] + bb[c]);
}

// ---------------- LayerNorm (wave-per-row), dual f32/bf16 out ----------------
__global__ __launch_bounds__(256) void ln2_kernel(
    const float* __restrict__ X, const float* __restrict__ g,
    const float* __restrict__ bb, float* __restrict__ outf,
    ushort* __restrict__ outb, int R)
{
  int wave = threadIdx.x >> 6, lane = threadIdx.x & 63;
  int row = blockIdx.x * 4 + wave;
  if (row >= R) return;
  float4 x = *(const float4*)(X + (size_t)row * 256 + lane * 4);
  float s = x.x + x.y + x.z + x.w;
  for (int o = 1; o < 64; o <<= 1) s += __shfl_xor(s, o);
  float mean = s * (1.0f / 256.0f);
  float d0 = x.x - mean, d1 = x.y - mean, d2 = x.z - mean, d3 = x.w - mean;
  float q = d0 * d0 + d1 * d1 + d2 * d2 + d3 * d3;
  for (int o = 1; o < 64; o <<= 1) q += __shfl_xor(q, o);
  float rs = rsqrtf(q * (1.0f / 256.0f) + kEPS);
  float4 gg = *(const float4*)(g + lane * 4);
  float4 bv = *(const float4*)(bb + lane * 4);
  float y0 = d0 * rs * gg.x + bv.x;
  float y1 = d1 * rs * gg.y + bv.y;
  float y2 = d2 * rs * gg.z + bv.z;
  float y3 = d3 * rs * gg.w + bv.w;
  if (outf) *(float4*)(outf + (size_t)row * 256 + lane * 4) = make_float4(y0, y1, y2, y3);
  if (outb) {
    ushort4 o4;
    o4.x = f2b(y0); o4.y = f2b(y1); o4.z = f2b(y2); o4.w = f2b(y3);
    *(ushort4*)(outb + (size_t)row * 256 + lane * 4) = o4;
  }
}

// ---------------- weight convert + transpose: Wt[c][k] = bf16(W[k][c]) ----------------
__global__ __launch_bounds__(256) void wconv_kernel(
    const float* __restrict__ W, ushort* __restrict__ Wt, int K, int C)
{
  __shared__ float t[32][33];
  const float* Wl = W + (size_t)blockIdx.z * K * C;
  ushort* Wtl = Wt + (size_t)blockIdx.z * K * C;
  int k0 = blockIdx.x * 32, c0 = blockIdx.y * 32;
  int tx = threadIdx.x & 31, ty = threadIdx.x >> 5;
  for (int i = ty; i < 32; i += 8) t[i][tx] = Wl[(size_t)(k0 + i) * C + c0 + tx];
  __syncthreads();
  for (int i = ty; i < 32; i += 8)
    Wtl[(size_t)(c0 + i) * K + k0 + tx] = f2b(t[tx][i]);
}

// ---------------- batched bf16 MFMA GEMM ----------------
struct GDesc {
  const ushort* A; const ushort* Bt; const float* bias; const float* res; void* out;
  int R, K, C, flags;          // flags: 1 relu, 2 bf16-out, 4 transposed-Vt-out
  int in_rpb, out_rpb, out_off, vt_stride;
};
struct GBatch { GDesc d[5]; };

__global__ __launch_bounds__(256) void gemmx_kernel(GBatch bt)
{
  GDesc d = bt.d[blockIdx.z];
  int r0 = blockIdx.x * 64;
  if (r0 >= d.R) return;
  int c0 = blockIdx.y * 64;

  __shared__ ushort As[4096]; // [row][chunk]: chunk c holds global k-chunk c^(row&7)
  __shared__ ushort Bs[4096];
  int tid = threadIdx.x;
  int lam = tid & 63, wv = tid >> 6;
  int wr = wv >> 1, wc = wv & 1;
  int K = d.K;
  int srow8 = lam >> 3;              // 0..7
  int sxor = (lam & 7) ^ srow8;      // pre-swizzled source chunk

  f32x4 acc[2][2] = {};

  for (int k0 = 0; k0 < K; k0 += 64) {
    #pragma unroll
    for (int i = 0; i < 2; ++i) {
      int row = 16 * wv + 8 * i + srow8;
      gld16(As + wv * 1024 + i * 512,
            d.A + (size_t)(r0 + row) * K + k0 + 8 * sxor);
      gld16(Bs + wv * 1024 + i * 512,
            d.Bt + (size_t)(c0 + row) * K + k0 + 8 * sxor);
    }
    __syncthreads();
    #pragma unroll
    for (int ks = 0; ks < 2; ++ks) {
      short8 af[2], bf_[2];
      #pragma unroll
      for (int m = 0; m < 2; ++m) {
        int ra = wr * 32 + m * 16 + (lam & 15);
        int ch = (ks * 4 + (lam >> 4)) ^ (ra & 7);
        af[m] = *(const short8*)(As + ra * 64 + ch * 8);
      }
      #pragma unroll
      for (int n = 0; n < 2; ++n) {
        int rb = wc * 32 + n * 16 + (lam & 15);
        int ch = (ks * 4 + (lam >> 4)) ^ (rb & 7);
        bf_[n] = *(const short8*)(Bs + rb * 64 + ch * 8);
      }
      #pragma unroll
      for (int m = 0; m < 2; ++m)
        #pragma unroll
        for (int n = 0; n < 2; ++n)
          acc[m][n] = __builtin_amdgcn_mfma_f32_16x16x32_bf16(
              af[m], bf_[n], acc[m][n], 0, 0, 0);
    }
    __syncthreads();
  }

  if (!(d.flags & 4)) {
    #pragma unroll
    for (int m = 0; m < 2; ++m) {
      #pragma unroll
      for (int reg = 0; reg < 4; ++reg) {
        int gr = r0 + wr * 32 + m * 16 + (lam >> 4) * 4 + reg;
        int bidx = gr / d.in_rpb, rr = gr - bidx * d.in_rpb;
        size_t orow = (size_t)bidx * d.out_rpb + d.out_off + rr;
        #pragma unroll
        for (int n = 0; n < 2; ++n) {
          int gc = c0 + wc * 32 + n * 16 + (lam & 15);
          float v = acc[m][n][reg] + d.bias[gc];
          if (d.res) v += d.res[(size_t)gr * d.C + gc];
          if (d.flags & 1) v = fmaxf(v, 0.f);
          if (d.flags & 2) ((ushort*)d.out)[orow * d.C + gc] = f2b(v);
          else ((float*)d.out)[orow * d.C + gc] = v;
        }
      }
    }
  } else {
    // transposed output: Vt[bidx][c][out_off + rr], via LDS transpose (reuse As)
    #pragma unroll
    for (int m = 0; m < 2; ++m)
      #pragma unroll
      for (int n = 0; n < 2; ++n)
        #pragma unroll
        for (int reg = 0; reg < 4; ++reg) {
          int col = wc * 32 + n * 16 + (lam & 15);
          int row = wr * 32 + m * 16 + (lam >> 4) * 4 + reg;
          float v = acc[m][n][reg] + d.bias[c0 + col];
          As[col * 64 + (((row >> 3) ^ (col & 7)) << 3) + (row & 7)] = f2b(v);
        }
    __syncthreads();
    int col2 = tid >> 2, rc = tid & 3;
    #pragma unroll
    for (int u = 0; u < 2; ++u) {
      int rowc = rc * 2 + u;
      short8 val = *(const short8*)(As + col2 * 64 + ((rowc ^ (col2 & 7)) << 3));
      int r = r0 + rowc * 8;
      int bidx = r / d.in_rpb, rr = r - bidx * d.in_rpb;
      *(short8*)((ushort*)d.out +
                 ((size_t)bidx * 256 + c0 + col2) * d.vt_stride + d.out_off + rr) = val;
    }
  }
}

// ---------------- MFMA flash attention v3: split-K, barrier-free, no K/V LDS ----------------
// Q bf16 [b][Sq][256]; K bf16 rows [b*k_rpb+key][256]; Vt bf16 [b*256+d][vt_stride].
// Each block: 4 independent waves x 16 q-rows, keys [s*slen, (s+1)*slen).
// Partial record (per q-row per split, 20 f32 = 80B): [m, l, 32 x bf16 acc].
__global__ __launch_bounds__(256) void attn3_kernel(
    const ushort* __restrict__ Qp, const ushort* __restrict__ Kp,
    const ushort* __restrict__ Vt, float* __restrict__ Pp,
    const float* __restrict__ maskf,
    int Sq, int k_rpb, int vt_stride, int self_off, int slen, int ns)
{
  __shared__ ushort P_lds[4][16][80];  // per-wave P^T [q][key]
  int bh = blockIdx.x;
  int b = bh >> 3, h = bh & 7;
  int sidx = blockIdx.z;
  int tid = threadIdx.x;
  int wave = tid >> 6, lane = tid & 63;
  int qlane = lane & 15, g = lane >> 4;
  int gq = blockIdx.y * 64 + wave * 16 + qlane;
  const float scale2 = 0.17677669529663688f * 1.4426950408889634f; // 1/sqrt(32)*log2e
  const float BIGM = 1e10f * scale2;

  short8 qB = *(const short8*)(Qp + ((size_t)(b * Sq + gq)) * 256 + h * 32 + g * 8);

  float mi = -3.0e38f, li = 0.f;
  f32x4 acc0 = {}, acc1 = {};

  if (self_off >= 0 && sidx == 0) {
    const ushort* kr = Kp + ((size_t)(b * k_rpb + self_off + gq)) * 256 + h * 32 + g * 8;
    short8 k8 = *(const short8*)kr;
    float part = 0.f;
    #pragma unroll
    for (int j = 0; j < 8; ++j) part += b2f((ushort)qB[j]) * b2f((ushort)k8[j]);
    part += __shfl_xor(part, 16);
    part += __shfl_xor(part, 32);
    mi = part * scale2;
    li = 1.f;
    const ushort* vb = Vt + ((size_t)(b * 256 + h * 32)) * vt_stride + self_off + gq;
    #pragma unroll
    for (int r = 0; r < 4; ++r) {
      acc0[r] = b2f(vb[(size_t)(4 * g + r) * vt_stride]);
      acc1[r] = b2f(vb[(size_t)(16 + 4 * g + r) * vt_stride]);
    }
  }

  const ushort* Kbase = Kp + ((size_t)b * k_rpb) * 256 + h * 32 + g * 8;
  const ushort* V0 = Vt + ((size_t)(b * 256 + h * 32 + qlane)) * vt_stride;
  const ushort* V1 = Vt + ((size_t)(b * 256 + h * 32 + 16 + qlane)) * vt_stride;
  const float* mbase = maskf + (size_t)b * kN;

  int n0 = sidx * slen;
  int ntile = slen >> 6;
  for (int it = 0; it < ntile; ++it, n0 += 64) {
    float p[4][4];
    float tm = -3.0e38f;
    #pragma unroll
    for (int f = 0; f < 4; ++f) {
      short8 kf = *(const short8*)(Kbase + (size_t)(n0 + 16 * f + qlane) * 256);
      f32x4 st = __builtin_amdgcn_mfma_f32_16x16x32_bf16(
          kf, qB, (f32x4){0.f, 0.f, 0.f, 0.f}, 0, 0, 0);
      float4 m4 = *(const float4*)(mbase + n0 + 16 * f + 4 * g);
      float mm[4] = {m4.x, m4.y, m4.z, m4.w};
      #pragma unroll
      for (int r = 0; r < 4; ++r) {
        float s = st[r] * scale2 + (mm[r] - 1.f) * BIGM;
        p[f][r] = s;
        tm = fmaxf(tm, s);
      }
    }
    tm = fmaxf(tm, __shfl_xor(tm, 16));
    tm = fmaxf(tm, __shfl_xor(tm, 32));
    if (__any(tm > mi + 11.5f)) {      // defer-max
      float nm = fmaxf(mi, tm);
      float fs = exp2f(mi - nm);
      li *= fs; mi = nm;
      #pragma unroll
      for (int r = 0; r < 4; ++r) { acc0[r] *= fs; acc1[r] *= fs; }
    }
    float ls = 0.f;
    #pragma unroll
    for (int f = 0; f < 4; ++f)
      #pragma unroll
      for (int r = 0; r < 4; ++r) {
        float pv = exp2f(p[f][r] - mi);
        p[f][r] = pv;
        ls += pv;
      }
    ls += __shfl_xor(ls, 16);
    ls += __shfl_xor(ls, 32);
    li += ls;

    // P^T -> per-wave LDS (bf16); same-wave write->read, no barrier needed
    #pragma unroll
    for (int f = 0; f < 4; ++f) {
      uint2 w;
      w.x = cvtpk(p[f][0], p[f][1]);
      w.y = cvtpk(p[f][2], p[f][3]);
      *(uint2*)&P_lds[wave][qlane][f * 16 + 4 * g] = w;
    }
    #pragma unroll
    for (int t = 0; t < 2; ++t) {
      short8 pb = *(const short8*)&P_lds[wave][qlane][32 * t + 8 * g];
      short8 vf0 = *(const short8*)(V0 + n0 + 32 * t + 8 * g);
      acc0 = __builtin_amdgcn_mfma_f32_16x16x32_bf16(vf0, pb, acc0, 0, 0, 0);
      short8 vf1 = *(const short8*)(V1 + n0 + 32 * t + 8 * g);
      acc1 = __builtin_amdgcn_mfma_f32_16x16x32_bf16(vf1, pb, acc1, 0, 0, 0);
    }
  }

  float* rec = Pp + ((size_t)(bh * Sq + gq) * ns + sidx) * 20;
  if (g == 0) { rec[0] = mi; rec[1] = li; }
  ushort* accp = (ushort*)(rec + 2);
  uint2 w0, w1;
  w0.x = cvtpk(acc0[0], acc0[1]); w0.y = cvtpk(acc0[2], acc0[3]);
  w1.x = cvtpk(acc1[0], acc1[1]); w1.y = cvtpk(acc1[2], acc1[3]);
  *(uint2*)(accp + 4 * g) = w0;
  *(uint2*)(accp + 16 + 4 * g) = w1;
}

// ---------------- split-K combine: merge ns partials, write bf16 AO ----------------
__global__ __launch_bounds__(256) void combine_kernel(
    const float* __restrict__ Pp, ushort* __restrict__ AO, int Sq, int ns)
{
  int r = blockIdx.x * 8 + (threadIdx.x >> 5);
  int d = threadIdx.x & 31;
  int bh = r / Sq, q = r - bh * Sq;
  int b = bh >> 3, h = bh & 7;
  const float* rb = Pp + (size_t)r * ns * 20;
  float M = -3.0e38f;
  for (int s2 = 0; s2 < ns; ++s2) M = fmaxf(M, rb[s2 * 20]);
  float L = 0.f, O = 0.f;
  for (int s2 = 0; s2 < ns; ++s2) {
    float w = exp2f(rb[s2 * 20] - M);
    L += rb[s2 * 20 + 1] * w;
    O += w * b2f(((const ushort*)(rb + s2 * 20 + 2))[d]);
  }
  AO[((size_t)(b * Sq + q)) * 256 + h * 32 + d] = f2b(O / L);
}

// ---------------- fused cls attention (one block per (b,h)) ----------------
__global__ __launch_bounds__(256) void cls_attn_kernel(
    const float* __restrict__ cls_s,
    const ushort* __restrict__ WqT, const float* __restrict__ bq,
    const ushort* __restrict__ WkT, const float* __restrict__ bk,
    const ushort* __restrict__ WvT, const float* __restrict__ bv,
    const ushort* __restrict__ Kbig, const ushort* __restrict__ Vt,
    float* __restrict__ AOc)
{
  __shared__ float c0f[256], qv[32], k0v[32], v0v[32];
  __shared__ float red[256];
  __shared__ float sarr[2560];
  __shared__ float scl[4]; // s_cls, M, L, p_cls
  const float scale2 = 0.17677669529663688f * 1.4426950408889634f;
  int b = blockIdx.x >> 3, h = blockIdx.x & 7;
  int t = threadIdx.x;
  c0f[t] = cls_s[b * 256 + t];
  __syncthreads();

  const ushort* Wm[3] = {WqT, WkT, WvT};
  const float* Bi[3] = {bq, bk, bv};
  float* Ov[3] = {qv, k0v, v0v};
  for (int pi = 0; pi < 3; ++pi) {
    int d = t >> 3, sl = t & 7;
    const ushort* wrow = Wm[pi] + (size_t)(h * 32 + d) * 256 + sl * 32;
    float part = 0.f;
    #pragma unroll
    for (int j = 0; j < 32; j += 8) {
      short8 w8 = *(const short8*)(wrow + j);
      #pragma unroll
      for (int jj = 0; jj < 8; ++jj) part += c0f[sl * 32 + j + jj] * b2f((ushort)w8[jj]);
    }
    red[t] = part;
    __syncthreads();
    if (t < 32) {
      float sum = 0.f;
      #pragma unroll
      for (int s = 0; s < 8; ++s) sum += red[t * 8 + s];
      Ov[pi][t] = sum + Bi[pi][h * 32 + t];
    }
    __syncthreads();
  }

  if (t < 32) red[t] = qv[t] * k0v[t];
  __syncthreads();
  if (t == 0) {
    float sc = 0.f;
    for (int j = 0; j < 32; ++j) sc += red[j];
    scl[0] = sc * scale2;
  }
  __syncthreads();

  float lmax = -3.0e38f;
  for (int it = 0; it < 10; ++it) {
    int key = t + it * 256;
    const ushort* krow = Kbig + ((size_t)(b * kKV + key)) * 256 + h * 32;
    float sdot = 0.f;
    #pragma unroll
    for (int j = 0; j < 4; ++j) {
      short8 k8 = ((const short8*)krow)[j];
      #pragma unroll
      for (int jj = 0; jj < 8; ++jj) sdot += qv[j * 8 + jj] * b2f((ushort)k8[jj]);
    }
    sdot *= scale2;
    sarr[key] = sdot;
    lmax = fmaxf(lmax, sdot);
  }
  red[t] = lmax;
  __syncthreads();
  for (int s = 128; s > 0; s >>= 1) { if (t < s) red[t] = fmaxf(red[t], red[t + s]); __syncthreads(); }
  if (t == 0) scl[1] = fmaxf(red[0], scl[0]);
  __syncthreads();
  float M = scl[1];
  float lsum = 0.f;
  for (int it = 0; it < 10; ++it) {
    int key = t + it * 256;
    float pv = exp2f(sarr[key] - M);
    sarr[key] = pv;
    lsum += pv;
  }
  red[t] = lsum;
  __syncthreads();
  for (int s = 128; s > 0; s >>= 1) { if (t < s) red[t] += red[t + s]; __syncthreads(); }
  if (t == 0) {
    scl[3] = exp2f(scl[0] - M);
    scl[2] = red[0] + scl[3];
  }
  __syncthreads();

  {
    int d = t & 31, sl = t >> 5;
    const ushort* vrow = Vt + ((size_t)(b * 256 + h * 32 + d)) * kKV + sl * 320;
    float acc = 0.f;
    for (int j = 0; j < 320; j += 8) {
      short8 v8 = *(const short8*)(vrow + j);
      #pragma unroll
      for (int jj = 0; jj < 8; ++jj) acc += sarr[sl * 320 + j + jj] * b2f((ushort)v8[jj]);
    }
    red[sl * 32 + d] = acc;
  }
  __syncthreads();
  if (t < 32) {
    float o = scl[3] * v0v[t];
    #pragma unroll
    for (int s = 0; s < 8; ++s) o += red[s * 32 + t];
    AOc[b * 256 + h * 32 + t] = o / scl[2];
  }
}

// ---------------- fused cls MLP: Wd+res+LN, FF1, FF2+res+LN ----------------
__device__ inline float blk_sum(float v, float* red, int t) {
  red[t] = v; __syncthreads();
  for (int s = 128; s > 0; s >>= 1) { if (t < s) red[t] += red[t + s]; __syncthreads(); }
  float r = red[0]; __syncthreads();
  return r;
}

__global__ __launch_bounds__(256) void cls_mlp_kernel(
    const float* __restrict__ AOc, float* __restrict__ cls_s,
    const ushort* __restrict__ WdT, const float* __restrict__ bd,
    const float* __restrict__ ag, const float* __restrict__ ab,
    const ushort* __restrict__ W1T, const float* __restrict__ b1,
    const ushort* __restrict__ W2T, const float* __restrict__ b2,
    const float* __restrict__ fg, const float* __restrict__ fb)
{
  __shared__ float oL[256], r0L[256], aL[256], ffL[1024], red[256];
  int b = blockIdx.x, t = threadIdx.x;
  oL[t] = AOc[b * 256 + t];
  r0L[t] = cls_s[b * 256 + t];
  __syncthreads();

  float v = bd[t] + r0L[t];
  {
    const ushort* wr_ = WdT + (size_t)t * 256;
    for (int j = 0; j < 256; j += 8) {
      short8 w8 = *(const short8*)(wr_ + j);
      #pragma unroll
      for (int jj = 0; jj < 8; ++jj) v += oL[j + jj] * b2f((ushort)w8[jj]);
    }
  }
  float mean = blk_sum(v, red, t) * (1.0f / 256.0f);
  float dv = v - mean;
  float var = blk_sum(dv * dv, red, t) * (1.0f / 256.0f);
  float a = dv * rsqrtf(var + kEPS) * ag[t] + ab[t];
  aL[t] = a;
  __syncthreads();

  for (int jj = 0; jj < 4; ++jj) {
    int c = jj * 256 + t;
    const ushort* w1r = W1T + (size_t)c * 256;
    float hv = b1[c];
    for (int j = 0; j < 256; j += 8) {
      short8 w8 = *(const short8*)(w1r + j);
      #pragma unroll
      for (int k2 = 0; k2 < 8; ++k2) hv += aL[j + k2] * b2f((ushort)w8[k2]);
    }
    ffL[c] = fmaxf(hv, 0.f);
  }
  __syncthreads();

  float v2 = b2[t] + aL[t];
  {
    const ushort* w2r = W2T + (size_t)t * 1024;
    for (int j = 0; j < 1024; j += 8) {
      short8 w8 = *(const short8*)(w2r + j);
      #pragma unroll
      for (int jj = 0; jj < 8; ++jj) v2 += ffL[j + jj] * b2f((ushort)w8[jj]);
    }
  }
  float mean2 = blk_sum(v2, red, t) * (1.0f / 256.0f);
  float dv2 = v2 - mean2;
  float var2 = blk_sum(dv2 * dv2, red, t) * (1.0f / 256.0f);
  cls_s[b * 256 + t] = dv2 * rsqrtf(var2 + kEPS) * fg[t] + fb[t];
}

__global__ void cls_init_kernel(const float* __restrict__ cf, float* __restrict__ cls)
{
  int i = blockIdx.x * 256 + threadIdx.x;
  cls[i] = cf[i & 255];
}

__global__ __launch_bounds__(256) void copyout_kernel(
    const float* __restrict__ qs, const float* __restrict__ ks,
    const float* __restrict__ cls, float* __restrict__ out)
{
  int i = blockIdx.x * 256 + threadIdx.x;
  float v;
  if (i < 262144) v = qs[i];
  else if (i < 1310720) v = ks[i - 262144];
  else v = cls[i - 1310720];
  out[i] = v;
}

extern "C" void kernel_launch(void* const* d_in, const int* in_sizes, int n_in,
                              void* d_out, int out_size, void* d_ws, size_t ws_size,
                              hipStream_t stream)
{
  const float* qc2    = (const float*)d_in[0];
  const float* qf2    = (const float*)d_in[1];
  const float* qf3    = (const float*)d_in[2];
  const float* kc2    = (const float*)d_in[3];
  const float* kf2    = (const float*)d_in[4];
  const float* kf3    = (const float*)d_in[5];
  const unsigned char* mraw = (const unsigned char*)d_in[6];
  const float* ln1_g  = (const float*)d_in[7];
  const float* ln1_b  = (const float*)d_in[8];
  const float* dc_W   = (const float*)d_in[9];
  const float* dc_b   = (const float*)d_in[10];
  const float* dcln_g = (const float*)d_in[11];
  const float* dcln_b = (const float*)d_in[12];
  const float* cls_f  = (const float*)d_in[13];
  const float* Wq     = (const float*)d_in[14];
  const float* bq     = (const float*)d_in[15];
  const float* Wk     = (const float*)d_in[16];
  const float* bk     = (const float*)d_in[17];
  const float* Wv     = (const float*)d_in[18];
  const float* bv     = (const float*)d_in[19];
  const float* Wd     = (const float*)d_in[20];
  const float* bd     = (const float*)d_in[21];
  const float* aln_g  = (const float*)d_in[22];
  const float* aln_b  = (const float*)d_in[23];
  const float* W1     = (const float*)d_in[24];
  const float* b1     = (const float*)d_in[25];
  const float* W2     = (const float*)d_in[26];
  const float* b2     = (const float*)d_in[27];
  const float* fln_g  = (const float*)d_in[28];
  const float* fln_b  = (const float*)d_in[29];

  float* ws = (float*)d_ws;
  float* maskf = ws + 0;        // 4096
  float* qs_s  = ws + 4096;     // 262144
  float* ks_s  = ws + 266240;   // 1048576
  float* cls_s = ws + 1314816;  // 512
  float* AOc   = ws + 1315328;  // 512
  float* Scr   = ws + 1315840;  // 2764800 f32 scratch overlay region
  float* T1    = Scr;               // 1048576 (dead during attention)
  float* T2    = Scr + 1048576;     // 1048576
  float* ksPart = Scr;              // 32768*4*20 = 2621440 (overlays T1,T2,+)
  float* qsPart = Scr + 2097152;    // 8192*4*20 = 655360
  ushort* ub   = (ushort*)(ws + 4080640);
  ushort* qs_b   = ub + 0;          // 262144
  ushort* ks_b   = ub + 262144;     // 1048576
  ushort* T2b    = ub + 1310720;    // 1048576
  ushort* Kbig   = ub + 2359296;    // 1310720 (B x 2560 x 256)
  ushort* Vt_ks  = ub + 3670016;    // 1048576 (B x 256 x 2048)
  ushort* Vt_big = ub + 4718592;    // 1310720 (B x 256 x 2560)
  ushort* FFb    = ub + 6029312;    // 4194304 (overlays Qb|Kks|AOb|T1b)
  ushort* Qb     = FFb + 0;         // 1048576
  ushort* Kks    = FFb + 1048576;   // 1048576
  ushort* AOb    = FFb + 2097152;   // 1048576
  ushort* T1b    = FFb + 3145728;   // 1048576
  ushort* wts    = ub + 10223616;
  ushort* dcWt = wts;               // 65536
  ushort* WqT  = wts + 65536;       // 4 x 65536
  ushort* WkT  = WqT + 262144;
  ushort* WvT  = WkT + 262144;
  ushort* WdT  = WvT + 262144;
  ushort* W1T  = WdT + 262144;      // 4 x 262144
  ushort* W2T  = W1T + 1048576;     // 4 x 262144
  // total ~43.3 MB

  auto mk = [](const ushort* A, const ushort* Bt, const float* bias, const float* res,
               void* out, int R, int K, int C, int flags,
               int in_rpb, int out_rpb, int out_off, int vt_stride) {
    GDesc g; g.A = A; g.Bt = Bt; g.bias = bias; g.res = res; g.out = out;
    g.R = R; g.K = K; g.C = C; g.flags = flags; g.in_rpb = in_rpb;
    g.out_rpb = out_rpb; g.out_off = out_off; g.vt_stride = vt_stride; return g;
  };
  auto launch = [&](const GDesc* ds, int n) {
    GBatch bt{};
    int maxR = 0;
    for (int i = 0; i < n; ++i) { bt.d[i] = ds[i]; if (ds[i].R > maxR) maxR = ds[i].R; }
    gemmx_kernel<<<dim3(maxR / 64, ds[0].C / 64, n), 256, 0, stream>>>(bt);
  };
  auto ln = [&](const float* X, const float* g_, const float* b_, float* of,
                ushort* ob, int R) {
    ln2_kernel<<<R / 4, 256, 0, stream>>>(X, g_, b_, of, ob, R);
  };

  mask_norm_kernel<<<16, 256, 0, stream>>>(mraw, maskf);

  wconv_kernel<<<dim3(8, 8, 1), 256, 0, stream>>>(dc_W, dcWt, 256, 256);
  wconv_kernel<<<dim3(8, 8, 4), 256, 0, stream>>>(Wq, WqT, 256, 256);
  wconv_kernel<<<dim3(8, 8, 4), 256, 0, stream>>>(Wk, WkT, 256, 256);
  wconv_kernel<<<dim3(8, 8, 4), 256, 0, stream>>>(Wv, WvT, 256, 256);
  wconv_kernel<<<dim3(8, 8, 4), 256, 0, stream>>>(Wd, WdT, 256, 256);
  wconv_kernel<<<dim3(8, 32, 4), 256, 0, stream>>>(W1, W1T, 256, 1024);
  wconv_kernel<<<dim3(32, 8, 4), 256, 0, stream>>>(W2, W2T, 1024, 256);

  // ---- encoders ----
  encode_kernel<<<kB * kM, 256, 0, stream>>>(qc2, qf2, qf3, ln1_g, ln1_b, T1b);
  { GDesc d = mk(T1b, dcWt, dc_b, nullptr, T2, kB * kM, 256, 256, 0, kB * kM, kB * kM, 0, 0);
    launch(&d, 1); }
  ln(T2, dcln_g, dcln_b, qs_s, qs_b, kB * kM);
  encode_kernel<<<kB * kN, 256, 0, stream>>>(kc2, kf2, kf3, ln1_g, ln1_b, T1b);
  { GDesc d = mk(T1b, dcWt, dc_b, nullptr, T2, kB * kN, 256, 256, 0, kB * kN, kB * kN, 0, 0);
    launch(&d, 1); }
  ln(T2, dcln_g, dcln_b, ks_s, ks_b, kB * kN);
  cls_init_kernel<<<2, 256, 0, stream>>>(cls_f, cls_s);

  for (int i = 0; i < kL; ++i) {
    const ushort* Wq_i = WqT + (size_t)i * 65536;  const float* bq_i = bq + i * 256;
    const ushort* Wk_i = WkT + (size_t)i * 65536;  const float* bk_i = bk + i * 256;
    const ushort* Wv_i = WvT + (size_t)i * 65536;  const float* bv_i = bv + i * 256;
    const ushort* Wd_i = WdT + (size_t)i * 65536;  const float* bd_i = bd + i * 256;
    const float* ag_i = aln_g + i * 256;           const float* ab_i = aln_b + i * 256;
    const ushort* W1_i = W1T + (size_t)i * 262144; const float* b1_i = b1 + i * 1024;
    const ushort* W2_i = W2T + (size_t)i * 262144; const float* b2_i = b2 + i * 256;
    const float* fg_i = fln_g + i * 256;           const float* fb_i = fln_b + i * 256;
    int Rk = kB * kN, Rq = kB * kM;

    // ---- ks sublayer ----
    {
      GDesc ds[3] = {
        mk(ks_b, Wq_i, bq_i, nullptr, Qb,  Rk, 256, 256, 2, Rk, Rk, 0, 0),
        mk(ks_b, Wk_i, bk_i, nullptr, Kks, Rk, 256, 256, 2, Rk, Rk, 0, 0),
        mk(ks_b, Wv_i, bv_i, nullptr, Vt_ks, Rk, 256, 256, 4, kN, 0, 0, kN)};
      launch(ds, 3);
    }
    attn3_kernel<<<dim3(kB * 8, kN / 64, kNS), 256, 0, stream>>>(
        Qb, Kks, Vt_ks, ksPart, maskf, kN, kN, kN, -1, kN / kNS, kNS);
    combine_kernel<<<kB * 8 * kN / 8, 256, 0, stream>>>(ksPart, AOb, kN, kNS);
    { GDesc d = mk(AOb, Wd_i, bd_i, ks_s, T1, Rk, 256, 256, 0, Rk, Rk, 0, 0);
      launch(&d, 1); }
    ln(T1, ag_i, ab_i, T2, T2b, Rk);
    { GDesc d = mk(T2b, W1_i, b1_i, nullptr, FFb, Rk, 256, 1024, 1 | 2, Rk, Rk, 0, 0);
      launch(&d, 1); }
    { GDesc d = mk(FFb, W2_i, b2_i, T2, T1, Rk, 1024, 256, 0, Rk, Rk, 0, 0);
      launch(&d, 1); }
    ln(T1, fg_i, fb_i, ks_s, ks_b, Rk);

    // ---- qs sublayer (query_self, keys = new ks) ----
    {
      GDesc ds[5] = {
        mk(qs_b, Wq_i, bq_i, nullptr, Qb, Rq, 256, 256, 2, Rq, Rq, 0, 0),
        mk(ks_b, Wk_i, bk_i, nullptr, Kbig, Rk, 256, 256, 2, kN, kKV, 0, 0),
        mk(ks_b, Wv_i, bv_i, nullptr, Vt_big, Rk, 256, 256, 4, kN, 0, 0, kKV),
        mk(qs_b, Wk_i, bk_i, nullptr, Kbig, Rq, 256, 256, 2, kM, kKV, kN, 0),
        mk(qs_b, Wv_i, bv_i, nullptr, Vt_big, Rq, 256, 256, 4, kM, 0, kN, kKV)};
      launch(ds, 5);
    }
    attn3_kernel<<<dim3(kB * 8, kM / 64, kNS), 256, 0, stream>>>(
        Qb, Kbig, Vt_big, qsPart, maskf, kM, kKV, kKV, kN, kN / kNS, kNS);
    combine_kernel<<<kB * 8 * kM / 8, 256, 0, stream>>>(qsPart, AOb, kM, kNS);
    { GDesc d = mk(AOb, Wd_i, bd_i, qs_s, T1, Rq, 256, 256, 0, Rq, Rq, 0, 0);
      launch(&d, 1); }
    ln(T1, ag_i, ab_i, T2, T2b, Rq);
    { GDesc d = mk(T2b, W1_i, b1_i, nullptr, FFb, Rq, 256, 1024, 1 | 2, Rq, Rq, 0, 0);
      launch(&d, 1); }
    { GDesc d = mk(FFb, W2_i, b2_i, T2, T1, Rq, 1024, 256, 0, Rq, Rq, 0, 0);
      launch(&d, 1); }
    ln(T1, fg_i, fb_i, qs_s, qs_b, Rq);

    // ---- cls sublayer ----
    {
      GDesc ds[2] = {
        mk(qs_b, Wk_i, bk_i, nullptr, Kbig, Rq, 256, 256, 2, kM, kKV, kN, 0),
        mk(qs_b, Wv_i, bv_i, nullptr, Vt_big, Rq, 256, 256, 4, kM, 0, kN, kKV)};
      launch(ds, 2);
    }
    cls_attn_kernel<<<16, 256, 0, stream>>>(cls_s, Wq_i, bq_i, Wk_i,
                                            bk_i, Wv_i, bv_i,
                                            Kbig, Vt_big, AOc);
    cls_mlp_kernel<<<2, 256, 0, stream>>>(AOc, cls_s, Wd_i, bd_i, ag_i, ab_i,
                                          W1_i, b1_i, W2_i, b2_i, fg_i, fb_i);
  }

  copyout_kernel<<<5122, 256, 0, stream>>>(qs_s, ks_s, cls_s, (float*)d_out);
}

// Round 6
// 1183.029 us; speedup vs baseline: 1.0514x; 1.0514x over previous
//
#include <hip/hip_runtime.h>
#include <math.h>

namespace {
constexpr int kB = 2;
constexpr int kM = 512;
constexpr int kN = 2048;
constexpr int kHID = 256;
constexpr int kDH = 32;
constexpr int kL = 4;
constexpr float kEPS = 1e-5f;
constexpr int kKV = 2560; // Kbig rows / Vt_big cols per batch (2048 ks + 512 qs)
constexpr int kNS = 4;    // attention key splits
}

typedef __attribute__((ext_vector_type(8))) short short8;
typedef __attribute__((ext_vector_type(4))) float f32x4;

__device__ inline ushort f2b(float f) {
  unsigned u = __builtin_bit_cast(unsigned, f);
  unsigned r = (u + 0x7fffu + ((u >> 16) & 1u)) >> 16;
  return (ushort)r;
}
__device__ inline float b2f(ushort u) {
  return __builtin_bit_cast(float, (unsigned)u << 16);
}
__device__ inline unsigned cvtpk(float lo, float hi) {
  unsigned r;
  asm("v_cvt_pk_bf16_f32 %0, %1, %2" : "=v"(r) : "v"(lo), "v"(hi));
  return r;
}
__device__ inline void gld16(ushort* lds, const ushort* g) {
  __builtin_amdgcn_global_load_lds(
      (const __attribute__((address_space(1))) void*)g,
      (__attribute__((address_space(3))) void*)lds, 16, 0, 0);
}

// ---------------- mask normalization (dtype sniffing) -> additive mask ----------------
// writes 0.f for visible keys, -BIG (already in log2-score domain) for masked.
__global__ __launch_bounds__(256) void mask_norm_kernel(
    const unsigned char* __restrict__ mraw, float* __restrict__ mf)
{
  int tid = threadIdx.x;
  __shared__ unsigned sh[4];
  if (tid < 4) sh[tid] = 0;
  __syncthreads();
  unsigned l1 = 0, l2 = 0, l3 = 0, l4 = 0;
  for (int j = 0; j < 16; ++j) {
    int p = tid * 16 + j;
    unsigned v = mraw[p];
    int r = p & 3;
    if (r == 1) l1 |= v;
    else if (r == 2) l2 |= v;
    else if (r == 3) l3 |= v;
    else if ((p & 7) == 4) l4 |= v;
  }
  if (l1) atomicOr(&sh[0], l1);
  if (l2) atomicOr(&sh[1], l2);
  if (l3) atomicOr(&sh[2], l3);
  if (l4) atomicOr(&sh[3], l4);
  __syncthreads();
  unsigned a1 = sh[0], a2 = sh[1], a3 = sh[2], a4 = sh[3];
  int mode; // 0=u8, 1=i32, 2=i64, 3=f32
  if ((a1 | a2 | a3) == 0) mode = a4 ? 1 : 2;
  else if (a1 == 0 && (a2 & ~0x80u) == 0 && (a3 & ~0x3Fu) == 0 && ((a2 | a3) != 0))
    mode = 3;
  else mode = 0;

  int i = blockIdx.x * 256 + tid;
  unsigned char v;
  if (mode == 0) v = mraw[i];
  else if (mode == 1) v = mraw[i * 4];
  else if (mode == 2) v = mraw[i * 8];
  else v = mraw[i * 4 + 3];
  mf[i] = v ? 0.f : -2.5505654e9f; // -(1e10 * scale2)
}

// ---------------- encoder: sinenc + add + LN1 -> bf16 ----------------
__global__ __launch_bounds__(256) void encode_kernel(
    const float* __restrict__ c2d, const float* __restrict__ f2,
    const float* __restrict__ f3, const float* __restrict__ g,
    const float* __restrict__ bb, ushort* __restrict__ out)
{
  int row = blockIdx.x;
  int c = threadIdx.x;
  float coord = c2d[(size_t)row * 2 + (c >> 7)];
  int h = c & 127;
  float ex = (float)(h & ~1) * (1.0f / 128.0f);
  float inv = expf(ex * 9.210340371976184f); // 10000^ex
  float val = coord / inv;
  float e = (h & 1) ? cosf(val) : sinf(val);
  float x = f2[(size_t)row * 256 + c] + f3[(size_t)row * 256 + c] + e;
  __shared__ float red[256];
  red[c] = x; __syncthreads();
  for (int s = 128; s > 0; s >>= 1) { if (c < s) red[c] += red[c + s]; __syncthreads(); }
  float mean = red[0] * (1.0f / 256.0f);
  __syncthreads();
  float d = x - mean;
  red[c] = d * d; __syncthreads();
  for (int s = 128; s > 0; s >>= 1) { if (c < s) red[c] += red[c + s]; __syncthreads(); }
  float var = red[0] * (1.0f / 256.0f);
  out[(size_t)row * 256 + c] = f2b(d * rsqrtf(var + kEPS) * g[c] + bb[c]);
}

// ---------------- LayerNorm (wave-per-row), dual f32/bf16 out ----------------
__global__ __launch_bounds__(256) void ln2_kernel(
    const float* __restrict__ X, const float* __restrict__ g,
    const float* __restrict__ bb, float* __restrict__ outf,
    ushort* __restrict__ outb, int R)
{
  int wave = threadIdx.x >> 6, lane = threadIdx.x & 63;
  int row = blockIdx.x * 4 + wave;
  if (row >= R) return;
  float4 x = *(const float4*)(X + (size_t)row * 256 + lane * 4);
  float s = x.x + x.y + x.z + x.w;
  for (int o = 1; o < 64; o <<= 1) s += __shfl_xor(s, o);
  float mean = s * (1.0f / 256.0f);
  float d0 = x.x - mean, d1 = x.y - mean, d2 = x.z - mean, d3 = x.w - mean;
  float q = d0 * d0 + d1 * d1 + d2 * d2 + d3 * d3;
  for (int o = 1; o < 64; o <<= 1) q += __shfl_xor(q, o);
  float rs = rsqrtf(q * (1.0f / 256.0f) + kEPS);
  float4 gg = *(const float4*)(g + lane * 4);
  float4 bv = *(const float4*)(bb + lane * 4);
  float y0 = d0 * rs * gg.x + bv.x;
  float y1 = d1 * rs * gg.y + bv.y;
  float y2 = d2 * rs * gg.z + bv.z;
  float y3 = d3 * rs * gg.w + bv.w;
  if (outf) *(float4*)(outf + (size_t)row * 256 + lane * 4) = make_float4(y0, y1, y2, y3);
  if (outb) {
    ushort4 o4;
    o4.x = f2b(y0); o4.y = f2b(y1); o4.z = f2b(y2); o4.w = f2b(y3);
    *(ushort4*)(outb + (size_t)row * 256 + lane * 4) = o4;
  }
}

// ---------------- weight convert + transpose: Wt[c][k] = bf16(W[k][c]) ----------------
__global__ __launch_bounds__(256) void wconv_kernel(
    const float* __restrict__ W, ushort* __restrict__ Wt, int K, int C)
{
  __shared__ float t[32][33];
  const float* Wl = W + (size_t)blockIdx.z * K * C;
  ushort* Wtl = Wt + (size_t)blockIdx.z * K * C;
  int k0 = blockIdx.x * 32, c0 = blockIdx.y * 32;
  int tx = threadIdx.x & 31, ty = threadIdx.x >> 5;
  for (int i = ty; i < 32; i += 8) t[i][tx] = Wl[(size_t)(k0 + i) * C + c0 + tx];
  __syncthreads();
  for (int i = ty; i < 32; i += 8)
    Wtl[(size_t)(c0 + i) * K + k0 + tx] = f2b(t[tx][i]);
}

// ---------------- batched bf16 MFMA GEMM ----------------
struct GDesc {
  const ushort* A; const ushort* Bt; const float* bias; const float* res; void* out;
  int R, K, C, flags;          // flags: 1 relu, 2 bf16-out, 4 transposed-Vt-out
  int in_rpb, out_rpb, out_off, vt_stride;
};
struct GBatch { GDesc d[5]; };

__global__ __launch_bounds__(256) void gemmx_kernel(GBatch bt)
{
  GDesc d = bt.d[blockIdx.z];
  int r0 = blockIdx.x * 64;
  if (r0 >= d.R) return;
  int c0 = blockIdx.y * 64;

  __shared__ ushort As[4096]; // [row][chunk]: chunk c holds global k-chunk c^(row&7)
  __shared__ ushort Bs[4096];
  int tid = threadIdx.x;
  int lam = tid & 63, wv = tid >> 6;
  int wr = wv >> 1, wc = wv & 1;
  int K = d.K;
  int srow8 = lam >> 3;              // 0..7
  int sxor = (lam & 7) ^ srow8;      // pre-swizzled source chunk

  f32x4 acc[2][2] = {};

  for (int k0 = 0; k0 < K; k0 += 64) {
    #pragma unroll
    for (int i = 0; i < 2; ++i) {
      int row = 16 * wv + 8 * i + srow8;
      gld16(As + wv * 1024 + i * 512,
            d.A + (size_t)(r0 + row) * K + k0 + 8 * sxor);
      gld16(Bs + wv * 1024 + i * 512,
            d.Bt + (size_t)(c0 + row) * K + k0 + 8 * sxor);
    }
    __syncthreads();
    #pragma unroll
    for (int ks = 0; ks < 2; ++ks) {
      short8 af[2], bf_[2];
      #pragma unroll
      for (int m = 0; m < 2; ++m) {
        int ra = wr * 32 + m * 16 + (lam & 15);
        int ch = (ks * 4 + (lam >> 4)) ^ (ra & 7);
        af[m] = *(const short8*)(As + ra * 64 + ch * 8);
      }
      #pragma unroll
      for (int n = 0; n < 2; ++n) {
        int rb = wc * 32 + n * 16 + (lam & 15);
        int ch = (ks * 4 + (lam >> 4)) ^ (rb & 7);
        bf_[n] = *(const short8*)(Bs + rb * 64 + ch * 8);
      }
      #pragma unroll
      for (int m = 0; m < 2; ++m)
        #pragma unroll
        for (int n = 0; n < 2; ++n)
          acc[m][n] = __builtin_amdgcn_mfma_f32_16x16x32_bf16(
              af[m], bf_[n], acc[m][n], 0, 0, 0);
    }
    __syncthreads();
  }

  if (!(d.flags & 4)) {
    #pragma unroll
    for (int m = 0; m < 2; ++m) {
      #pragma unroll
      for (int reg = 0; reg < 4; ++reg) {
        int gr = r0 + wr * 32 + m * 16 + (lam >> 4) * 4 + reg;
        int bidx = gr / d.in_rpb, rr = gr - bidx * d.in_rpb;
        size_t orow = (size_t)bidx * d.out_rpb + d.out_off + rr;
        #pragma unroll
        for (int n = 0; n < 2; ++n) {
          int gc = c0 + wc * 32 + n * 16 + (lam & 15);
          float v = acc[m][n][reg] + d.bias[gc];
          if (d.res) v += d.res[(size_t)gr * d.C + gc];
          if (d.flags & 1) v = fmaxf(v, 0.f);
          if (d.flags & 2) ((ushort*)d.out)[orow * d.C + gc] = f2b(v);
          else ((float*)d.out)[orow * d.C + gc] = v;
        }
      }
    }
  } else {
    // transposed output: Vt[bidx][c][out_off + rr], via LDS transpose (reuse As)
    #pragma unroll
    for (int m = 0; m < 2; ++m)
      #pragma unroll
      for (int n = 0; n < 2; ++n)
        #pragma unroll
        for (int reg = 0; reg < 4; ++reg) {
          int col = wc * 32 + n * 16 + (lam & 15);
          int row = wr * 32 + m * 16 + (lam >> 4) * 4 + reg;
          float v = acc[m][n][reg] + d.bias[c0 + col];
          As[col * 64 + (((row >> 3) ^ (col & 7)) << 3) + (row & 7)] = f2b(v);
        }
    __syncthreads();
    int col2 = tid >> 2, rc = tid & 3;
    #pragma unroll
    for (int u = 0; u < 2; ++u) {
      int rowc = rc * 2 + u;
      short8 val = *(const short8*)(As + col2 * 64 + ((rowc ^ (col2 & 7)) << 3));
      int r = r0 + rowc * 8;
      int bidx = r / d.in_rpb, rr = r - bidx * d.in_rpb;
      *(short8*)((ushort*)d.out +
                 ((size_t)bidx * 256 + c0 + col2) * d.vt_stride + d.out_off + rr) = val;
    }
  }
}

// ---------------- MFMA flash attention v4: split-K, reg-pipelined, LDS-free ----------------
// Q bf16 [b][Sq][256]; K bf16 rows [b*k_rpb+key][256]; Vt bf16 [b*256+d][vt_stride].
// 2-deep K prefetch ping-pong; V/mask issued early in each compute; P^T via 8 shfl.
// Partial record (per q-row per split, 20 f32 = 80B): [m, l, 32 x bf16 acc].
__global__ __launch_bounds__(256) void attn4_kernel(
    const ushort* __restrict__ Qp, const ushort* __restrict__ Kp,
    const ushort* __restrict__ Vt, float* __restrict__ Pp,
    const float* __restrict__ madd,
    int Sq, int k_rpb, int vt_stride, int self_off, int slen, int ns)
{
  int bh = blockIdx.x;
  int b = bh >> 3, h = bh & 7;
  int sidx = blockIdx.z;
  int tid = threadIdx.x;
  int lane = tid & 63;
  int qlane = lane & 15, g = lane >> 4;
  int gq = blockIdx.y * 64 + (tid >> 6) * 16 + qlane;
  const float scale2 = 0.17677669529663688f * 1.4426950408889634f; // 1/sqrt(32)*log2e

  short8 qB = *(const short8*)(Qp + ((size_t)(b * Sq + gq)) * 256 + h * 32 + g * 8);

  float mi = -3.0e38f, li = 0.f;
  f32x4 acc0 = {}, acc1 = {};

  if (self_off >= 0 && sidx == 0) {
    const ushort* kr = Kp + ((size_t)(b * k_rpb + self_off + gq)) * 256 + h * 32 + g * 8;
    short8 k8 = *(const short8*)kr;
    float part = 0.f;
    #pragma unroll
    for (int j = 0; j < 8; ++j) part += b2f((ushort)qB[j]) * b2f((ushort)k8[j]);
    part += __shfl_xor(part, 16);
    part += __shfl_xor(part, 32);
    mi = part * scale2;
    li = 1.f;
    const ushort* vb = Vt + ((size_t)(b * 256 + h * 32)) * vt_stride + self_off + gq;
    #pragma unroll
    for (int r = 0; r < 4; ++r) {
      acc0[r] = b2f(vb[(size_t)(4 * g + r) * vt_stride]);
      acc1[r] = b2f(vb[(size_t)(16 + 4 * g + r) * vt_stride]);
    }
  }

  const ushort* Kb = Kp + ((size_t)b * k_rpb) * 256 + h * 32 + g * 8;
  const ushort* V0 = Vt + ((size_t)(b * 256 + h * 32 + qlane)) * vt_stride;
  const ushort* V1 = V0 + (size_t)16 * vt_stride;
  const float* mb = madd + (size_t)b * kN;

  int base = sidx * slen;
  int ntile = slen >> 6; // 8, even

  auto loadK = [&](short8* D, int n0) {
    #pragma unroll
    for (int f = 0; f < 4; ++f)
      D[f] = *(const short8*)(Kb + (size_t)(n0 + 16 * f + qlane) * 256);
  };

  auto compute = [&](const short8* Kf, int n0) {
    // V + mask issued early: latency rides under QK^T + softmax
    short8 v00 = *(const short8*)(V0 + n0 + 8 * g);
    short8 v01 = *(const short8*)(V0 + n0 + 32 + 8 * g);
    short8 v10 = *(const short8*)(V1 + n0 + 8 * g);
    short8 v11 = *(const short8*)(V1 + n0 + 32 + 8 * g);
    float4 m4[4];
    #pragma unroll
    for (int f = 0; f < 4; ++f)
      m4[f] = *(const float4*)(mb + n0 + 16 * f + 4 * g);

    f32x4 st[4];
    #pragma unroll
    for (int f = 0; f < 4; ++f)
      st[f] = __builtin_amdgcn_mfma_f32_16x16x32_bf16(
          Kf[f], qB, (f32x4){0.f, 0.f, 0.f, 0.f}, 0, 0, 0);

    float p[4][4];
    float tm = -3.0e38f;
    #pragma unroll
    for (int f = 0; f < 4; ++f) {
      float mm[4] = {m4[f].x, m4[f].y, m4[f].z, m4[f].w};
      #pragma unroll
      for (int r = 0; r < 4; ++r) {
        float s = fmaf(st[f][r], scale2, mm[r]);
        p[f][r] = s;
        tm = fmaxf(tm, s);
      }
    }
    tm = fmaxf(tm, __shfl_xor(tm, 16));
    tm = fmaxf(tm, __shfl_xor(tm, 32));
    if (__any(tm > mi + 11.5f)) {  // defer-max
      float nm = fmaxf(mi, tm);
      float fs = exp2f(mi - nm);
      li *= fs; mi = nm;
      #pragma unroll
      for (int r = 0; r < 4; ++r) { acc0[r] *= fs; acc1[r] *= fs; }
    }
    float ls = 0.f;
    #pragma unroll
    for (int f = 0; f < 4; ++f)
      #pragma unroll
      for (int r = 0; r < 4; ++r) {
        float pv = exp2f(p[f][r] - mi);
        p[f][r] = pv;
        ls += pv;
      }
    ls += __shfl_xor(ls, 16);
    ls += __shfl_xor(ls, 32);
    li += ls;

    // P^T -> bf16 B-fragments via pack + 8 shfl per 32-key half (r3-verified)
    unsigned pkw[4][2];
    #pragma unroll
    for (int f = 0; f < 4; ++f) {
      pkw[f][0] = cvtpk(p[f][0], p[f][1]);
      pkw[f][1] = cvtpk(p[f][2], p[f][3]);
    }
    int src0 = qlane | ((2 * (g & 1)) << 4);
    int src1 = src0 + 16;
    bool hi = g >= 2;
    #pragma unroll
    for (int t = 0; t < 2; ++t) {
      unsigned t0 = (unsigned)__shfl((int)pkw[2 * t][0], src0);
      unsigned t1 = (unsigned)__shfl((int)pkw[2 * t][1], src0);
      unsigned t2 = (unsigned)__shfl((int)pkw[2 * t][0], src1);
      unsigned t3 = (unsigned)__shfl((int)pkw[2 * t][1], src1);
      unsigned u0 = (unsigned)__shfl((int)pkw[2 * t + 1][0], src0);
      unsigned u1 = (unsigned)__shfl((int)pkw[2 * t + 1][1], src0);
      unsigned u2 = (unsigned)__shfl((int)pkw[2 * t + 1][0], src1);
      unsigned u3 = (unsigned)__shfl((int)pkw[2 * t + 1][1], src1);
      union { unsigned u[4]; short8 v; } pb;
      pb.u[0] = hi ? u0 : t0;
      pb.u[1] = hi ? u1 : t1;
      pb.u[2] = hi ? u2 : t2;
      pb.u[3] = hi ? u3 : t3;
      acc0 = __builtin_amdgcn_mfma_f32_16x16x32_bf16(t ? v01 : v00, pb.v, acc0, 0, 0, 0);
      acc1 = __builtin_amdgcn_mfma_f32_16x16x32_bf16(t ? v11 : v10, pb.v, acc1, 0, 0, 0);
    }
  };

  short8 Ka[4], Kc[4];
  loadK(Ka, base);
  for (int it = 0; it < ntile; it += 2) {
    loadK(Kc, base + (it + 1) * 64);
    compute(Ka, base + it * 64);
    loadK(Ka, (it + 2 < ntile) ? (base + (it + 2) * 64) : base);
    compute(Kc, base + (it + 1) * 64);
  }

  float* rec = Pp + ((size_t)(bh * Sq + gq) * ns + sidx) * 20;
  if (g == 0) { rec[0] = mi; rec[1] = li; }
  ushort* accp = (ushort*)(rec + 2);
  uint2 w0, w1;
  w0.x = cvtpk(acc0[0], acc0[1]); w0.y = cvtpk(acc0[2], acc0[3]);
  w1.x = cvtpk(acc1[0], acc1[1]); w1.y = cvtpk(acc1[2], acc1[3]);
  *(uint2*)(accp + 4 * g) = w0;
  *(uint2*)(accp + 16 + 4 * g) = w1;
}

// ---------------- split-K combine: merge ns partials, write bf16 AO ----------------
__global__ __launch_bounds__(256) void combine_kernel(
    const float* __restrict__ Pp, ushort* __restrict__ AO, int Sq, int ns)
{
  int r = blockIdx.x * 8 + (threadIdx.x >> 5);
  int d = threadIdx.x & 31;
  int bh = r / Sq, q = r - bh * Sq;
  int b = bh >> 3, h = bh & 7;
  const float* rb = Pp + (size_t)r * ns * 20;
  float M = -3.0e38f;
  for (int s2 = 0; s2 < ns; ++s2) M = fmaxf(M, rb[s2 * 20]);
  float L = 0.f, O = 0.f;
  for (int s2 = 0; s2 < ns; ++s2) {
    float w = exp2f(rb[s2 * 20] - M);
    L += rb[s2 * 20 + 1] * w;
    O += w * b2f(((const ushort*)(rb + s2 * 20 + 2))[d]);
  }
  AO[((size_t)(b * Sq + q)) * 256 + h * 32 + d] = f2b(O / L);
}

// ---------------- fused cls attention (one block per (b,h)) ----------------
__global__ __launch_bounds__(256) void cls_attn_kernel(
    const float* __restrict__ cls_s,
    const ushort* __restrict__ WqT, const float* __restrict__ bq,
    const ushort* __restrict__ WkT, const float* __restrict__ bk,
    const ushort* __restrict__ WvT, const float* __restrict__ bv,
    const ushort* __restrict__ Kbig, const ushort* __restrict__ Vt,
    float* __restrict__ AOc)
{
  __shared__ float c0f[256], qv[32], k0v[32], v0v[32];
  __shared__ float red[256];
  __shared__ float sarr[2560];
  __shared__ float scl[4]; // s_cls, M, L, p_cls
  const float scale2 = 0.17677669529663688f * 1.4426950408889634f;
  int b = blockIdx.x >> 3, h = blockIdx.x & 7;
  int t = threadIdx.x;
  c0f[t] = cls_s[b * 256 + t];
  __syncthreads();

  const ushort* Wm[3] = {WqT, WkT, WvT};
  const float* Bi[3] = {bq, bk, bv};
  float* Ov[3] = {qv, k0v, v0v};
  for (int pi = 0; pi < 3; ++pi) {
    int d = t >> 3, sl = t & 7;
    const ushort* wrow = Wm[pi] + (size_t)(h * 32 + d) * 256 + sl * 32;
    float part = 0.f;
    #pragma unroll
    for (int j = 0; j < 32; j += 8) {
      short8 w8 = *(const short8*)(wrow + j);
      #pragma unroll
      for (int jj = 0; jj < 8; ++jj) part += c0f[sl * 32 + j + jj] * b2f((ushort)w8[jj]);
    }
    red[t] = part;
    __syncthreads();
    if (t < 32) {
      float sum = 0.f;
      #pragma unroll
      for (int s = 0; s < 8; ++s) sum += red[t * 8 + s];
      Ov[pi][t] = sum + Bi[pi][h * 32 + t];
    }
    __syncthreads();
  }

  if (t < 32) red[t] = qv[t] * k0v[t];
  __syncthreads();
  if (t == 0) {
    float sc = 0.f;
    for (int j = 0; j < 32; ++j) sc += red[j];
    scl[0] = sc * scale2;
  }
  __syncthreads();

  float lmax = -3.0e38f;
  for (int it = 0; it < 10; ++it) {
    int key = t + it * 256;
    const ushort* krow = Kbig + ((size_t)(b * kKV + key)) * 256 + h * 32;
    float sdot = 0.f;
    #pragma unroll
    for (int j = 0; j < 4; ++j) {
      short8 k8 = ((const short8*)krow)[j];
      #pragma unroll
      for (int jj = 0; jj < 8; ++jj) sdot += qv[j * 8 + jj] * b2f((ushort)k8[jj]);
    }
    sdot *= scale2;
    sarr[key] = sdot;
    lmax = fmaxf(lmax, sdot);
  }
  red[t] = lmax;
  __syncthreads();
  for (int s = 128; s > 0; s >>= 1) { if (t < s) red[t] = fmaxf(red[t], red[t + s]); __syncthreads(); }
  if (t == 0) scl[1] = fmaxf(red[0], scl[0]);
  __syncthreads();
  float M = scl[1];
  float lsum = 0.f;
  for (int it = 0; it < 10; ++it) {
    int key = t + it * 256;
    float pv = exp2f(sarr[key] - M);
    sarr[key] = pv;
    lsum += pv;
  }
  red[t] = lsum;
  __syncthreads();
  for (int s = 128; s > 0; s >>= 1) { if (t < s) red[t] += red[t + s]; __syncthreads(); }
  if (t == 0) {
    scl[3] = exp2f(scl[0] - M);
    scl[2] = red[0] + scl[3];
  }
  __syncthreads();

  {
    int d = t & 31, sl = t >> 5;
    const ushort* vrow = Vt + ((size_t)(b * 256 + h * 32 + d)) * kKV + sl * 320;
    float acc = 0.f;
    for (int j = 0; j < 320; j += 8) {
      short8 v8 = *(const short8*)(vrow + j);
      #pragma unroll
      for (int jj = 0; jj < 8; ++jj) acc += sarr[sl * 320 + j + jj] * b2f((ushort)v8[jj]);
    }
    red[sl * 32 + d] = acc;
  }
  __syncthreads();
  if (t < 32) {
    float o = scl[3] * v0v[t];
    #pragma unroll
    for (int s = 0; s < 8; ++s) o += red[s * 32 + t];
    AOc[b * 256 + h * 32 + t] = o / scl[2];
  }
}

// ---------------- fused cls MLP: Wd+res+LN, FF1, FF2+res+LN ----------------
__device__ inline float blk_sum(float v, float* red, int t) {
  red[t] = v; __syncthreads();
  for (int s = 128; s > 0; s >>= 1) { if (t < s) red[t] += red[t + s]; __syncthreads(); }
  float r = red[0]; __syncthreads();
  return r;
}

__global__ __launch_bounds__(256) void cls_mlp_kernel(
    const float* __restrict__ AOc, float* __restrict__ cls_s,
    const ushort* __restrict__ WdT, const float* __restrict__ bd,
    const float* __restrict__ ag, const float* __restrict__ ab,
    const ushort* __restrict__ W1T, const float* __restrict__ b1,
    const ushort* __restrict__ W2T, const float* __restrict__ b2,
    const float* __restrict__ fg, const float* __restrict__ fb)
{
  __shared__ float oL[256], r0L[256], aL[256], ffL[1024], red[256];
  int b = blockIdx.x, t = threadIdx.x;
  oL[t] = AOc[b * 256 + t];
  r0L[t] = cls_s[b * 256 + t];
  __syncthreads();

  float v = bd[t] + r0L[t];
  {
    const ushort* wr_ = WdT + (size_t)t * 256;
    for (int j = 0; j < 256; j += 8) {
      short8 w8 = *(const short8*)(wr_ + j);
      #pragma unroll
      for (int jj = 0; jj < 8; ++jj) v += oL[j + jj] * b2f((ushort)w8[jj]);
    }
  }
  float mean = blk_sum(v, red, t) * (1.0f / 256.0f);
  float dv = v - mean;
  float var = blk_sum(dv * dv, red, t) * (1.0f / 256.0f);
  float a = dv * rsqrtf(var + kEPS) * ag[t] + ab[t];
  aL[t] = a;
  __syncthreads();

  for (int jj = 0; jj < 4; ++jj) {
    int c = jj * 256 + t;
    const ushort* w1r = W1T + (size_t)c * 256;
    float hv = b1[c];
    for (int j = 0; j < 256; j += 8) {
      short8 w8 = *(const short8*)(w1r + j);
      #pragma unroll
      for (int k2 = 0; k2 < 8; ++k2) hv += aL[j + k2] * b2f((ushort)w8[k2]);
    }
    ffL[c] = fmaxf(hv, 0.f);
  }
  __syncthreads();

  float v2 = b2[t] + aL[t];
  {
    const ushort* w2r = W2T + (size_t)t * 1024;
    for (int j = 0; j < 1024; j += 8) {
      short8 w8 = *(const short8*)(w2r + j);
      #pragma unroll
      for (int jj = 0; jj < 8; ++jj) v2 += ffL[j + jj] * b2f((ushort)w8[jj]);
    }
  }
  float mean2 = blk_sum(v2, red, t) * (1.0f / 256.0f);
  float dv2 = v2 - mean2;
  float var2 = blk_sum(dv2 * dv2, red, t) * (1.0f / 256.0f);
  cls_s[b * 256 + t] = dv2 * rsqrtf(var2 + kEPS) * fg[t] + fb[t];
}

__global__ void cls_init_kernel(const float* __restrict__ cf, float* __restrict__ cls)
{
  int i = blockIdx.x * 256 + threadIdx.x;
  cls[i] = cf[i & 255];
}

__global__ __launch_bounds__(256) void copyout_kernel(
    const float* __restrict__ qs, const float* __restrict__ ks,
    const float* __restrict__ cls, float* __restrict__ out)
{
  int i = blockIdx.x * 256 + threadIdx.x;
  float v;
  if (i < 262144) v = qs[i];
  else if (i < 1310720) v = ks[i - 262144];
  else v = cls[i - 1310720];
  out[i] = v;
}

extern "C" void kernel_launch(void* const* d_in, const int* in_sizes, int n_in,
                              void* d_out, int out_size, void* d_ws, size_t ws_size,
                              hipStream_t stream)
{
  const float* qc2    = (const float*)d_in[0];
  const float* qf2    = (const float*)d_in[1];
  const float* qf3    = (const float*)d_in[2];
  const float* kc2    = (const float*)d_in[3];
  const float* kf2    = (const float*)d_in[4];
  const float* kf3    = (const float*)d_in[5];
  const unsigned char* mraw = (const unsigned char*)d_in[6];
  const float* ln1_g  = (const float*)d_in[7];
  const float* ln1_b  = (const float*)d_in[8];
  const float* dc_W   = (const float*)d_in[9];
  const float* dc_b   = (const float*)d_in[10];
  const float* dcln_g = (const float*)d_in[11];
  const float* dcln_b = (const float*)d_in[12];
  const float* cls_f  = (const float*)d_in[13];
  const float* Wq     = (const float*)d_in[14];
  const float* bq     = (const float*)d_in[15];
  const float* Wk     = (const float*)d_in[16];
  const float* bk     = (const float*)d_in[17];
  const float* Wv     = (const float*)d_in[18];
  const float* bv     = (const float*)d_in[19];
  const float* Wd     = (const float*)d_in[20];
  const float* bd     = (const float*)d_in[21];
  const float* aln_g  = (const float*)d_in[22];
  const float* aln_b  = (const float*)d_in[23];
  const float* W1     = (const float*)d_in[24];
  const float* b1     = (const float*)d_in[25];
  const float* W2     = (const float*)d_in[26];
  const float* b2     = (const float*)d_in[27];
  const float* fln_g  = (const float*)d_in[28];
  const float* fln_b  = (const float*)d_in[29];

  float* ws = (float*)d_ws;
  float* maskf = ws + 0;        // 4096 (additive)
  float* qs_s  = ws + 4096;     // 262144
  float* ks_s  = ws + 266240;   // 1048576
  float* cls_s = ws + 1314816;  // 512
  float* AOc   = ws + 1315328;  // 512
  float* Scr   = ws + 1315840;  // scratch overlay region
  float* T1    = Scr;               // 1048576 (dead during attention)
  float* T2    = Scr + 1048576;     // 1048576
  float* ksPart = Scr;              // 32768*4*20 = 2621440 (overlays T1,T2,+)
  float* qsPart = Scr + 2097152;    // 8192*4*20 = 655360
  ushort* ub   = (ushort*)(ws + 4080640);
  ushort* qs_b   = ub + 0;          // 262144
  ushort* ks_b   = ub + 262144;     // 1048576
  ushort* T2b    = ub + 1310720;    // 1048576
  ushort* Kbig   = ub + 2359296;    // 1310720 (B x 2560 x 256)
  ushort* Vt_ks  = ub + 3670016;    // 1048576 (B x 256 x 2048)
  ushort* Vt_big = ub + 4718592;    // 1310720 (B x 256 x 2560)
  ushort* FFb    = ub + 6029312;    // 4194304 (overlays Qb|Kks|AOb|T1b)
  ushort* Qb     = FFb + 0;         // 1048576
  ushort* Kks    = FFb + 1048576;   // 1048576
  ushort* AOb    = FFb + 2097152;   // 1048576
  ushort* T1b    = FFb + 3145728;   // 1048576
  ushort* wts    = ub + 10223616;
  ushort* dcWt = wts;               // 65536
  ushort* WqT  = wts + 65536;       // 4 x 65536
  ushort* WkT  = WqT + 262144;
  ushort* WvT  = WkT + 262144;
  ushort* WdT  = WvT + 262144;
  ushort* W1T  = WdT + 262144;      // 4 x 262144
  ushort* W2T  = W1T + 1048576;     // 4 x 262144
  // total ~43.3 MB

  auto mk = [](const ushort* A, const ushort* Bt, const float* bias, const float* res,
               void* out, int R, int K, int C, int flags,
               int in_rpb, int out_rpb, int out_off, int vt_stride) {
    GDesc g; g.A = A; g.Bt = Bt; g.bias = bias; g.res = res; g.out = out;
    g.R = R; g.K = K; g.C = C; g.flags = flags; g.in_rpb = in_rpb;
    g.out_rpb = out_rpb; g.out_off = out_off; g.vt_stride = vt_stride; return g;
  };
  auto launch = [&](const GDesc* ds, int n) {
    GBatch bt{};
    int maxR = 0;
    for (int i = 0; i < n; ++i) { bt.d[i] = ds[i]; if (ds[i].R > maxR) maxR = ds[i].R; }
    gemmx_kernel<<<dim3(maxR / 64, ds[0].C / 64, n), 256, 0, stream>>>(bt);
  };
  auto ln = [&](const float* X, const float* g_, const float* b_, float* of,
                ushort* ob, int R) {
    ln2_kernel<<<R / 4, 256, 0, stream>>>(X, g_, b_, of, ob, R);
  };

  mask_norm_kernel<<<16, 256, 0, stream>>>(mraw, maskf);

  wconv_kernel<<<dim3(8, 8, 1), 256, 0, stream>>>(dc_W, dcWt, 256, 256);
  wconv_kernel<<<dim3(8, 8, 4), 256, 0, stream>>>(Wq, WqT, 256, 256);
  wconv_kernel<<<dim3(8, 8, 4), 256, 0, stream>>>(Wk, WkT, 256, 256);
  wconv_kernel<<<dim3(8, 8, 4), 256, 0, stream>>>(Wv, WvT, 256, 256);
  wconv_kernel<<<dim3(8, 8, 4), 256, 0, stream>>>(Wd, WdT, 256, 256);
  wconv_kernel<<<dim3(8, 32, 4), 256, 0, stream>>>(W1, W1T, 256, 1024);
  wconv_kernel<<<dim3(32, 8, 4), 256, 0, stream>>>(W2, W2T, 1024, 256);

  // ---- encoders ----
  encode_kernel<<<kB * kM, 256, 0, stream>>>(qc2, qf2, qf3, ln1_g, ln1_b, T1b);
  { GDesc d = mk(T1b, dcWt, dc_b, nullptr, T2, kB * kM, 256, 256, 0, kB * kM, kB * kM, 0, 0);
    launch(&d, 1); }
  ln(T2, dcln_g, dcln_b, qs_s, qs_b, kB * kM);
  encode_kernel<<<kB * kN, 256, 0, stream>>>(kc2, kf2, kf3, ln1_g, ln1_b, T1b);
  { GDesc d = mk(T1b, dcWt, dc_b, nullptr, T2, kB * kN, 256, 256, 0, kB * kN, kB * kN, 0, 0);
    launch(&d, 1); }
  ln(T2, dcln_g, dcln_b, ks_s, ks_b, kB * kN);
  cls_init_kernel<<<2, 256, 0, stream>>>(cls_f, cls_s);

  for (int i = 0; i < kL; ++i) {
    const ushort* Wq_i = WqT + (size_t)i * 65536;  const float* bq_i = bq + i * 256;
    const ushort* Wk_i = WkT + (size_t)i * 65536;  const float* bk_i = bk + i * 256;
    const ushort* Wv_i = WvT + (size_t)i * 65536;  const float* bv_i = bv + i * 256;
    const ushort* Wd_i = WdT + (size_t)i * 65536;  const float* bd_i = bd + i * 256;
    const float* ag_i = aln_g + i * 256;           const float* ab_i = aln_b + i * 256;
    const ushort* W1_i = W1T + (size_t)i * 262144; const float* b1_i = b1 + i * 1024;
    const ushort* W2_i = W2T + (size_t)i * 262144; const float* b2_i = b2 + i * 256;
    const float* fg_i = fln_g + i * 256;           const float* fb_i = fln_b + i * 256;
    int Rk = kB * kN, Rq = kB * kM;

    // ---- ks sublayer ----
    {
      GDesc ds[3] = {
        mk(ks_b, Wq_i, bq_i, nullptr, Qb,  Rk, 256, 256, 2, Rk, Rk, 0, 0),
        mk(ks_b, Wk_i, bk_i, nullptr, Kks, Rk, 256, 256, 2, Rk, Rk, 0, 0),
        mk(ks_b, Wv_i, bv_i, nullptr, Vt_ks, Rk, 256, 256, 4, kN, 0, 0, kN)};
      launch(ds, 3);
    }
    attn4_kernel<<<dim3(kB * 8, kN / 64, kNS), 256, 0, stream>>>(
        Qb, Kks, Vt_ks, ksPart, maskf, kN, kN, kN, -1, kN / kNS, kNS);
    combine_kernel<<<kB * 8 * kN / 8, 256, 0, stream>>>(ksPart, AOb, kN, kNS);
    { GDesc d = mk(AOb, Wd_i, bd_i, ks_s, T1, Rk, 256, 256, 0, Rk, Rk, 0, 0);
      launch(&d, 1); }
    ln(T1, ag_i, ab_i, T2, T2b, Rk);
    { GDesc d = mk(T2b, W1_i, b1_i, nullptr, FFb, Rk, 256, 1024, 1 | 2, Rk, Rk, 0, 0);
      launch(&d, 1); }
    { GDesc d = mk(FFb, W2_i, b2_i, T2, T1, Rk, 1024, 256, 0, Rk, Rk, 0, 0);
      launch(&d, 1); }
    ln(T1, fg_i, fb_i, ks_s, ks_b, Rk);

    // ---- qs sublayer (query_self, keys = new ks) ----
    {
      GDesc ds[5] = {
        mk(qs_b, Wq_i, bq_i, nullptr, Qb, Rq, 256, 256, 2, Rq, Rq, 0, 0),
        mk(ks_b, Wk_i, bk_i, nullptr, Kbig, Rk, 256, 256, 2, kN, kKV, 0, 0),
        mk(ks_b, Wv_i, bv_i, nullptr, Vt_big, Rk, 256, 256, 4, kN, 0, 0, kKV),
        mk(qs_b, Wk_i, bk_i, nullptr, Kbig, Rq, 256, 256, 2, kM, kKV, kN, 0),
        mk(qs_b, Wv_i, bv_i, nullptr, Vt_big, Rq, 256, 256, 4, kM, 0, kN, kKV)};
      launch(ds, 5);
    }
    attn4_kernel<<<dim3(kB * 8, kM / 64, kNS), 256, 0, stream>>>(
        Qb, Kbig, Vt_big, qsPart, maskf, kM, kKV, kKV, kN, kN / kNS, kNS);
    combine_kernel<<<kB * 8 * kM / 8, 256, 0, stream>>>(qsPart, AOb, kM, kNS);
    { GDesc d = mk(AOb, Wd_i, bd_i, qs_s, T1, Rq, 256, 256, 0, Rq, Rq, 0, 0);
      launch(&d, 1); }
    ln(T1, ag_i, ab_i, T2, T2b, Rq);
    { GDesc d = mk(T2b, W1_i, b1_i, nullptr, FFb, Rq, 256, 1024, 1 | 2, Rq, Rq, 0, 0);
      launch(&d, 1); }
    { GDesc d = mk(FFb, W2_i, b2_i, T2, T1, Rq, 1024, 256, 0, Rq, Rq, 0, 0);
      launch(&d, 1); }
    ln(T1, fg_i, fb_i, qs_s, qs_b, Rq);

    // ---- cls sublayer ----
    {
      GDesc ds[2] = {
        mk(qs_b, Wk_i, bk_i, nullptr, Kbig, Rq, 256, 256, 2, kM, kKV, kN, 0),
        mk(qs_b, Wv_i, bv_i, nullptr, Vt_big, Rq, 256, 256, 4, kM, 0, kN, kKV)};
      launch(ds, 2);
    }
    cls_attn_kernel<<<16, 256, 0, stream>>>(cls_s, Wq_i, bq_i, Wk_i,
                                            bk_i, Wv_i, bv_i,
                                            Kbig, Vt_big, AOc);
    cls_mlp_kernel<<<2, 256, 0, stream>>>(AOc, cls_s, Wd_i, bd_i, ag_i, ab_i,
                                          W1_i, b1_i, W2_i, b2_i, fg_i, fb_i);
  }

  copyout_kernel<<<5122, 256, 0, stream>>>(qs_s, ks_s, cls_s, (float*)d_out);
}